// Round 1
// baseline (341.214 us; speedup 1.0000x reference)
//
#include <hip/hip_runtime.h>
#include <hip/hip_bf16.h>

// Problem constants (from setup_inputs): N=8192, D_IN=128, H=64, C=40, E=262144,
// TAU=0.25, T=4 -> steps=16.
constexpr int N_   = 8192;
constexpr int DIN_ = 128;
constexpr int H_   = 64;
constexpr int C_   = 40;
constexpr int STEPS_ = 16;
#define TAU_ 0.25f

// x0 = x_in @ enc_w + enc_b  (N x 128 @ 128 x 64). One wave handles 4 rows;
// lane j owns output column j; weight column loads are coalesced and reused 4x.
__global__ __launch_bounds__(256) void enc_k(const float* __restrict__ xin,
    const float* __restrict__ w, const float* __restrict__ b,
    float* __restrict__ x0)
{
    int wid  = (blockIdx.x * 256 + threadIdx.x) >> 6;
    int lane = threadIdx.x & 63;
    int r0 = wid * 4;
    if (r0 >= N_) return;
    const float* xr = xin + (size_t)r0 * DIN_;
    float bv = b[lane];
    float a0 = bv, a1 = bv, a2 = bv, a3 = bv;
    for (int k = 0; k < DIN_; ++k) {
        float wv = w[k * H_ + lane];
        a0 = fmaf(xr[k],            wv, a0);
        a1 = fmaf(xr[DIN_ + k],     wv, a1);
        a2 = fmaf(xr[2 * DIN_ + k], wv, a2);
        a3 = fmaf(xr[3 * DIN_ + k], wv, a3);
    }
    float* o = x0 + (size_t)r0 * H_ + lane;
    o[0] = a0; o[H_] = a1; o[2 * H_] = a2; o[3 * H_] = a3;
}

// kx = x0 @ wk_w + wk_b ; qx = x0 @ wq_w + wq_b  (fused, same geometry)
__global__ __launch_bounds__(256) void kq_k(const float* __restrict__ x0,
    const float* __restrict__ wk, const float* __restrict__ kb,
    const float* __restrict__ wq, const float* __restrict__ qb,
    float* __restrict__ kx, float* __restrict__ qx)
{
    int wid  = (blockIdx.x * 256 + threadIdx.x) >> 6;
    int lane = threadIdx.x & 63;
    int r0 = wid * 4;
    if (r0 >= N_) return;
    const float* xr = x0 + (size_t)r0 * H_;
    float kbv = kb[lane], qbv = qb[lane];
    float ak0 = kbv, ak1 = kbv, ak2 = kbv, ak3 = kbv;
    float aq0 = qbv, aq1 = qbv, aq2 = qbv, aq3 = qbv;
    for (int k = 0; k < H_; ++k) {
        float wkv = wk[k * H_ + lane];
        float wqv = wq[k * H_ + lane];
        float x0v = xr[k], x1v = xr[H_ + k], x2v = xr[2 * H_ + k], x3v = xr[3 * H_ + k];
        ak0 = fmaf(x0v, wkv, ak0);  aq0 = fmaf(x0v, wqv, aq0);
        ak1 = fmaf(x1v, wkv, ak1);  aq1 = fmaf(x1v, wqv, aq1);
        ak2 = fmaf(x2v, wkv, ak2);  aq2 = fmaf(x2v, wqv, aq2);
        ak3 = fmaf(x3v, wkv, ak3);  aq3 = fmaf(x3v, wqv, aq3);
    }
    float* ok = kx + (size_t)r0 * H_ + lane;
    float* oq = qx + (size_t)r0 * H_ + lane;
    ok[0] = ak0; ok[H_] = ak1; ok[2 * H_] = ak2; ok[3 * H_] = ak3;
    oq[0] = aq0; oq[H_] = aq1; oq[2 * H_] = aq2; oq[3 * H_] = aq3;
}

// Per edge: w = exp(dot(kx[u], qx[v]) / H). Dedup via N^2 bitmap (set-semantics:
// duplicates have identical w, so any single winner is exact). Kept edges
// accumulate row_sum[u] and deg[u].
__global__ __launch_bounds__(256) void edge_k(const int2* __restrict__ edges,
    const float* __restrict__ kx, const float* __restrict__ qx,
    float* __restrict__ w_e, float* __restrict__ row_sum, int* __restrict__ deg,
    unsigned long long* __restrict__ bitmap, int E)
{
    int e = blockIdx.x * 256 + threadIdx.x;
    if (e >= E) return;
    int2 uv = edges[e];
    int u = uv.x, v = uv.y;
    const float4* kr = (const float4*)(kx + (size_t)u * H_);
    const float4* qr = (const float4*)(qx + (size_t)v * H_);
    float dot = 0.f;
#pragma unroll
    for (int i = 0; i < H_ / 4; ++i) {
        float4 a = kr[i], b = qr[i];
        dot += a.x * b.x + a.y * b.y + a.z * b.z + a.w * b.w;
    }
    float w = expf(dot * (1.0f / (float)H_));
    size_t idx = (size_t)u * N_ + v;
    unsigned long long mask = 1ull << (idx & 63);
    unsigned long long old = atomicOr(&bitmap[idx >> 6], mask);
    if (old & mask) { w_e[e] = 0.0f; return; }  // duplicate (u,v): counted once
    w_e[e] = w;
    atomicAdd(&row_sum[u], w);
    atomicAdd(&deg[u], 1);
}

// Exclusive scan of deg -> row_ptr (and row_fill copy). Single block.
__global__ __launch_bounds__(256) void scan_k(const int* __restrict__ deg,
    int* __restrict__ row_ptr, int* __restrict__ row_fill)
{
    __shared__ int partial[257];
    int t = threadIdx.x;
    const int chunk = N_ / 256;
    int base = t * chunk;
    int s = 0;
    for (int i = 0; i < chunk; ++i) s += deg[base + i];
    partial[t] = s;
    __syncthreads();
    if (t == 0) {
        int run = 0;
        for (int i = 0; i < 256; ++i) { int tmp = partial[i]; partial[i] = run; run += tmp; }
        partial[256] = run;
    }
    __syncthreads();
    int run = partial[t];
    for (int i = 0; i < chunk; ++i) {
        row_ptr[base + i] = run;
        row_fill[base + i] = run;
        run += deg[base + i];
    }
    if (t == 255) row_ptr[N_] = run;
}

// Scatter kept edges into CSR; fold TAU / row_sum into the weight once.
__global__ __launch_bounds__(256) void place_k(const int2* __restrict__ edges,
    const float* __restrict__ w_e, const float* __restrict__ row_sum,
    int* __restrict__ row_fill, int* __restrict__ csr_v, float* __restrict__ csr_w, int E)
{
    int e = blockIdx.x * 256 + threadIdx.x;
    if (e >= E) return;
    float w = w_e[e];
    if (w == 0.0f) return;
    int2 uv = edges[e];
    int pos = atomicAdd(&row_fill[uv.x], 1);
    csr_v[pos] = uv.y;
    csr_w[pos] = TAU_ * w / row_sum[uv.x];
}

// y = 0.75*x + sum_e csr_w[e] * x[csr_v[e]]  — one wave per row, lane = column.
__global__ __launch_bounds__(256) void step_k(const float* __restrict__ x,
    float* __restrict__ y, const int* __restrict__ row_ptr,
    const int* __restrict__ csr_v, const float* __restrict__ csr_w)
{
    int row  = (blockIdx.x * 256 + threadIdx.x) >> 6;
    int lane = threadIdx.x & 63;
    if (row >= N_) return;
    int p0 = row_ptr[row], p1 = row_ptr[row + 1];
    float acc = (1.0f - TAU_) * x[(size_t)row * H_ + lane];
    int p = p0;
    for (; p + 1 < p1; p += 2) {
        int   v0 = csr_v[p],   v1 = csr_v[p + 1];
        float w0 = csr_w[p],   w1 = csr_w[p + 1];
        float xv0 = x[(size_t)v0 * H_ + lane];
        float xv1 = x[(size_t)v1 * H_ + lane];
        acc = fmaf(w0, xv0, acc);
        acc = fmaf(w1, xv1, acc);
    }
    if (p < p1) {
        acc = fmaf(csr_w[p], x[(size_t)csr_v[p] * H_ + lane], acc);
    }
    y[(size_t)row * H_ + lane] = acc;
}

// out = x @ dec_w + dec_b  (N x 64 @ 64 x 40). Wave handles 4 rows, lanes 0..39.
__global__ __launch_bounds__(256) void dec_k(const float* __restrict__ x,
    const float* __restrict__ dw, const float* __restrict__ db,
    float* __restrict__ out)
{
    int wid  = (blockIdx.x * 256 + threadIdx.x) >> 6;
    int lane = threadIdx.x & 63;
    int r0 = wid * 4;
    if (r0 >= N_ || lane >= C_) return;
    float bv = db[lane];
    float a0 = bv, a1 = bv, a2 = bv, a3 = bv;
    const float* xr = x + (size_t)r0 * H_;
    for (int k = 0; k < H_; ++k) {
        float dv = dw[k * C_ + lane];
        a0 = fmaf(xr[k],          dv, a0);
        a1 = fmaf(xr[H_ + k],     dv, a1);
        a2 = fmaf(xr[2 * H_ + k], dv, a2);
        a3 = fmaf(xr[3 * H_ + k], dv, a3);
    }
    out[(size_t)r0 * C_ + lane]       = a0;
    out[(size_t)(r0 + 1) * C_ + lane] = a1;
    out[(size_t)(r0 + 2) * C_ + lane] = a2;
    out[(size_t)(r0 + 3) * C_ + lane] = a3;
}

extern "C" void kernel_launch(void* const* d_in, const int* in_sizes, int n_in,
                              void* d_out, int out_size, void* d_ws, size_t ws_size,
                              hipStream_t stream)
{
    const float* x_in  = (const float*)d_in[0];
    const float* enc_w = (const float*)d_in[1];
    const float* enc_b = (const float*)d_in[2];
    const float* wk_w  = (const float*)d_in[3];
    const float* wk_b  = (const float*)d_in[4];
    const float* wq_w  = (const float*)d_in[5];
    const float* wq_b  = (const float*)d_in[6];
    const float* dec_w = (const float*)d_in[7];
    const float* dec_b = (const float*)d_in[8];
    const int2*  edges = (const int2*)d_in[9];
    const int E = in_sizes[9] / 2;   // 262144
    float* out = (float*)d_out;

    // Workspace layout (bytes):
    char* ws = (char*)d_ws;
    float* x0       = (float*)(ws + 0);                       // 2 MB  (N*64*4)
    float* xb       = (float*)(ws + (2u << 20));              // 2 MB
    float* kx       = (float*)(ws + (4u << 20));              // 2 MB
    float* qx       = (float*)(ws + (6u << 20));              // 2 MB
    float* w_e      = (float*)(ws + (8u << 20));              // 1 MB  (E*4)
    int*   csr_v    = (int*)  (ws + (9u << 20));              // 1 MB
    float* csr_w    = (float*)(ws + (10u << 20));             // 1 MB
    float* row_sum  = (float*)(ws + (11u << 20));             // 32 KB
    int*   deg      = (int*)  (ws + (11u << 20) + (64u << 10));   // 32 KB
    int*   row_ptr  = (int*)  (ws + (11u << 20) + (128u << 10));  // 32 KB + 4
    int*   row_fill = (int*)  (ws + (11u << 20) + (192u << 10));  // 32 KB
    unsigned long long* bitmap = (unsigned long long*)(ws + (12u << 20)); // 8 MB (N^2 bits)

    // Zero accumulators + dedup bitmap (every call; harness does not re-poison).
    hipMemsetAsync(row_sum, 0, (128u << 10), stream);          // row_sum + deg
    hipMemsetAsync(bitmap, 0, (size_t)N_ * N_ / 8, stream);

    enc_k<<<N_ / 16, 256, 0, stream>>>(x_in, enc_w, enc_b, x0);
    kq_k <<<N_ / 16, 256, 0, stream>>>(x0, wk_w, wk_b, wq_w, wq_b, kx, qx);
    edge_k<<<(E + 255) / 256, 256, 0, stream>>>(edges, kx, qx, w_e, row_sum, deg, bitmap, E);
    scan_k<<<1, 256, 0, stream>>>(deg, row_ptr, row_fill);
    place_k<<<(E + 255) / 256, 256, 0, stream>>>(edges, w_e, row_sum, row_fill, csr_v, csr_w, E);

    // 16 propagation steps: x <- 0.75*x + 0.25*A*x  (ping-pong x0 <-> xb)
    float* xa = x0;
    for (int s = 0; s < STEPS_; ++s) {
        step_k<<<N_ / 4, 256, 0, stream>>>(xa, (xa == x0) ? xb : x0, row_ptr, csr_v, csr_w);
        xa = (xa == x0) ? xb : x0;
    }
    // STEPS_=16 (even) -> final state back in x0
    dec_k<<<N_ / 16, 256, 0, stream>>>(xa, dec_w, dec_b, out);
}

// Round 2
// 257.329 us; speedup vs baseline: 1.3260x; 1.3260x over previous
//
#include <hip/hip_runtime.h>
#include <hip/hip_bf16.h>

// N=8192, D_IN=128, H=64, C=40, E=262144, TAU=0.25, T=4 -> 16 steps.
constexpr int N_   = 8192;
constexpr int DIN_ = 128;
constexpr int H_   = 64;
constexpr int C_   = 40;
constexpr int STEPS_ = 16;
#define TAU_ 0.25f

// x0 = x_in @ enc_w + enc_b  (N x 128 @ 128 x 64). Wave = 4 rows, lane = out col.
__global__ __launch_bounds__(256) void enc_k(const float* __restrict__ xin,
    const float* __restrict__ w, const float* __restrict__ b,
    float* __restrict__ x0)
{
    int wid  = (blockIdx.x * 256 + threadIdx.x) >> 6;
    int lane = threadIdx.x & 63;
    int r0 = wid * 4;
    if (r0 >= N_) return;
    const float* xr = xin + (size_t)r0 * DIN_;
    float bv = b[lane];
    float a0 = bv, a1 = bv, a2 = bv, a3 = bv;
    for (int k = 0; k < DIN_; ++k) {
        float wv = w[k * H_ + lane];
        a0 = fmaf(xr[k],            wv, a0);
        a1 = fmaf(xr[DIN_ + k],     wv, a1);
        a2 = fmaf(xr[2 * DIN_ + k], wv, a2);
        a3 = fmaf(xr[3 * DIN_ + k], wv, a3);
    }
    float* o = x0 + (size_t)r0 * H_ + lane;
    o[0] = a0; o[H_] = a1; o[2 * H_] = a2; o[3 * H_] = a3;
}

// kx = x0 @ wk_w + wk_b ; qx = x0 @ wq_w + wq_b  (fused)
__global__ __launch_bounds__(256) void kq_k(const float* __restrict__ x0,
    const float* __restrict__ wk, const float* __restrict__ kb,
    const float* __restrict__ wq, const float* __restrict__ qb,
    float* __restrict__ kx, float* __restrict__ qx)
{
    int wid  = (blockIdx.x * 256 + threadIdx.x) >> 6;
    int lane = threadIdx.x & 63;
    int r0 = wid * 4;
    if (r0 >= N_) return;
    const float* xr = x0 + (size_t)r0 * H_;
    float kbv = kb[lane], qbv = qb[lane];
    float ak0 = kbv, ak1 = kbv, ak2 = kbv, ak3 = kbv;
    float aq0 = qbv, aq1 = qbv, aq2 = qbv, aq3 = qbv;
    for (int k = 0; k < H_; ++k) {
        float wkv = wk[k * H_ + lane];
        float wqv = wq[k * H_ + lane];
        float x0v = xr[k], x1v = xr[H_ + k], x2v = xr[2 * H_ + k], x3v = xr[3 * H_ + k];
        ak0 = fmaf(x0v, wkv, ak0);  aq0 = fmaf(x0v, wqv, aq0);
        ak1 = fmaf(x1v, wkv, ak1);  aq1 = fmaf(x1v, wqv, aq1);
        ak2 = fmaf(x2v, wkv, ak2);  aq2 = fmaf(x2v, wqv, aq2);
        ak3 = fmaf(x3v, wkv, ak3);  aq3 = fmaf(x3v, wqv, aq3);
    }
    float* ok = kx + (size_t)r0 * H_ + lane;
    float* oq = qx + (size_t)r0 * H_ + lane;
    ok[0] = ak0; ok[H_] = ak1; ok[2 * H_] = ak2; ok[3 * H_] = ak3;
    oq[0] = aq0; oq[H_] = aq1; oq[2 * H_] = aq2; oq[3 * H_] = aq3;
}

// Degree count over ALL edges (dups included; dedup zeroes their weights later).
__global__ __launch_bounds__(256) void count_k(const int2* __restrict__ edges,
    int* __restrict__ deg, int E)
{
    int e = blockIdx.x * 256 + threadIdx.x;
    if (e >= E) return;
    atomicAdd(&deg[edges[e].x], 1);
}

// Exclusive scan of deg -> row_ptr, row_fill. Single block.
__global__ __launch_bounds__(256) void scan_k(const int* __restrict__ deg,
    int* __restrict__ row_ptr, int* __restrict__ row_fill)
{
    __shared__ int partial[257];
    int t = threadIdx.x;
    const int chunk = N_ / 256;
    int base = t * chunk;
    int s = 0;
    for (int i = 0; i < chunk; ++i) s += deg[base + i];
    partial[t] = s;
    __syncthreads();
    if (t == 0) {
        int run = 0;
        for (int i = 0; i < 256; ++i) { int tmp = partial[i]; partial[i] = run; run += tmp; }
        partial[256] = run;
    }
    __syncthreads();
    int run = partial[t];
    for (int i = 0; i < chunk; ++i) {
        row_ptr[base + i] = run;
        row_fill[base + i] = run;
        run += deg[base + i];
    }
    if (t == 255) row_ptr[N_] = run;
}

// Score + CSR placement. 16 lanes per edge: coalesced 256B row reads of kx/qx,
// 16-lane shfl reduce, lane 0 places (v, w=exp(dot/H)) via row_fill atomic.
__global__ __launch_bounds__(256) void score_place_k(const int2* __restrict__ edges,
    const float* __restrict__ kx, const float* __restrict__ qx,
    int* __restrict__ row_fill, int* __restrict__ csr_v, float* __restrict__ csr_w, int E)
{
    int t  = blockIdx.x * 256 + threadIdx.x;
    int eg = t >> 4;
    int sl = t & 15;
    if (eg >= E) return;
    int2 uv = edges[eg];
    float4 a = ((const float4*)(kx + (size_t)uv.x * H_))[sl];
    float4 b = ((const float4*)(qx + (size_t)uv.y * H_))[sl];
    float d = a.x * b.x + a.y * b.y + a.z * b.z + a.w * b.w;
    d += __shfl_xor(d, 1);
    d += __shfl_xor(d, 2);
    d += __shfl_xor(d, 4);
    d += __shfl_xor(d, 8);
    if (sl == 0) {
        float w = expf(d * (1.0f / (float)H_));
        int pos = atomicAdd(&row_fill[uv.x], 1);
        csr_v[pos] = uv.y;
        csr_w[pos] = w;
    }
}

// Per-row dedup (LDS bitmap, any-winner is exact since dup weights identical),
// row-sum reduce, fold TAU/row_sum, pack (v, w) -> int2 stream.
__global__ __launch_bounds__(256) void dedup_k(const int* __restrict__ row_ptr,
    const int* __restrict__ csr_v, const float* __restrict__ csr_w,
    int2* __restrict__ vw)
{
    __shared__ unsigned int bm[4][256];   // 8192 bits per wave
    int wv   = threadIdx.x >> 6;
    int lane = threadIdx.x & 63;
    int row  = blockIdx.x * 4 + wv;
    unsigned int* b = bm[wv];
    for (int i = lane; i < 256; i += 64) b[i] = 0;
    __syncthreads();
    int p0 = row_ptr[row], p1 = row_ptr[row + 1];
    float wsum = 0.f;
    for (int p = p0 + lane; p < p1; p += 64) {
        int v = csr_v[p];
        unsigned int m = 1u << (v & 31);
        unsigned int old = atomicOr(&b[v >> 5], m);
        float w = (old & m) ? 0.0f : csr_w[p];
        vw[p] = make_int2(v, __float_as_int(w));
        wsum += w;
    }
    #pragma unroll
    for (int off = 1; off < 64; off <<= 1) wsum += __shfl_xor(wsum, off);
    if (p0 == p1) return;                  // empty row
    float scale = TAU_ / wsum;
    for (int p = p0 + lane; p < p1; p += 64) {
        int2 e = vw[p];
        e.y = __float_as_int(__int_as_float(e.y) * scale);
        vw[p] = e;
    }
}

// y = 0.75*x + sum_e w_e * x[v_e]. One wave per row. The whole (v,w) row list
// is fetched in ONE coalesced 8B/lane load; entries broadcast via constant-index
// shfl (readlane); 16 independent gathers in flight per unrolled chunk.
__global__ __launch_bounds__(256) void step_k(const float* __restrict__ x,
    float* __restrict__ y, const int* __restrict__ row_ptr,
    const int2* __restrict__ vw)
{
    int row  = (blockIdx.x * 256 + threadIdx.x) >> 6;
    int lane = threadIdx.x & 63;
    float acc = (1.0f - TAU_) * x[(size_t)row * H_ + lane];
    int p0 = row_ptr[row], p1 = row_ptr[row + 1];
    for (int base = p0; base < p1; base += 64) {
        int rem = p1 - base;               // wave-uniform, > 0
        int2 e = (lane < rem) ? vw[base + lane] : make_int2(0, 0);
        #pragma unroll
        for (int i = 0; i < 64; i += 16) {
            if (i < rem) {                 // uniform branch
                #pragma unroll
                for (int j = 0; j < 16; ++j) {
                    int   v = __shfl(e.x, i + j);            // readlane (const idx)
                    float w = __int_as_float(__shfl(e.y, i + j));
                    acc = fmaf(w, x[(size_t)v * H_ + lane], acc);  // padded: w=0, x[0] L1-hot
                }
            }
        }
    }
    y[(size_t)row * H_ + lane] = acc;
}

// out = x @ dec_w + dec_b  (N x 64 @ 64 x 40). Wave = 4 rows, lanes 0..39.
__global__ __launch_bounds__(256) void dec_k(const float* __restrict__ x,
    const float* __restrict__ dw, const float* __restrict__ db,
    float* __restrict__ out)
{
    int wid  = (blockIdx.x * 256 + threadIdx.x) >> 6;
    int lane = threadIdx.x & 63;
    int r0 = wid * 4;
    if (r0 >= N_ || lane >= C_) return;
    float bv = db[lane];
    float a0 = bv, a1 = bv, a2 = bv, a3 = bv;
    const float* xr = x + (size_t)r0 * H_;
    for (int k = 0; k < H_; ++k) {
        float dv = dw[k * C_ + lane];
        a0 = fmaf(xr[k],          dv, a0);
        a1 = fmaf(xr[H_ + k],     dv, a1);
        a2 = fmaf(xr[2 * H_ + k], dv, a2);
        a3 = fmaf(xr[3 * H_ + k], dv, a3);
    }
    out[(size_t)r0 * C_ + lane]       = a0;
    out[(size_t)(r0 + 1) * C_ + lane] = a1;
    out[(size_t)(r0 + 2) * C_ + lane] = a2;
    out[(size_t)(r0 + 3) * C_ + lane] = a3;
}

extern "C" void kernel_launch(void* const* d_in, const int* in_sizes, int n_in,
                              void* d_out, int out_size, void* d_ws, size_t ws_size,
                              hipStream_t stream)
{
    const float* x_in  = (const float*)d_in[0];
    const float* enc_w = (const float*)d_in[1];
    const float* enc_b = (const float*)d_in[2];
    const float* wk_w  = (const float*)d_in[3];
    const float* wk_b  = (const float*)d_in[4];
    const float* wq_w  = (const float*)d_in[5];
    const float* wq_b  = (const float*)d_in[6];
    const float* dec_w = (const float*)d_in[7];
    const float* dec_b = (const float*)d_in[8];
    const int2*  edges = (const int2*)d_in[9];
    const int E = in_sizes[9] / 2;   // 262144
    float* out = (float*)d_out;

    char* ws = (char*)d_ws;
    float* x0       = (float*)(ws + 0);                           // 2 MB
    float* xb       = (float*)(ws + (2u << 20));                  // 2 MB
    float* kx       = (float*)(ws + (4u << 20));                  // 2 MB
    float* qx       = (float*)(ws + (6u << 20));                  // 2 MB
    int*   csr_v    = (int*)  (ws + (8u << 20));                  // 1 MB
    float* csr_w    = (float*)(ws + (9u << 20));                  // 1 MB
    int2*  vw       = (int2*) (ws + (10u << 20));                 // 2 MB
    int*   deg      = (int*)  (ws + (12u << 20));                 // 32 KB
    int*   row_ptr  = (int*)  (ws + (12u << 20) + (64u << 10));   // 32 KB + 4
    int*   row_fill = (int*)  (ws + (12u << 20) + (128u << 10));  // 32 KB

    hipMemsetAsync(deg, 0, N_ * sizeof(int), stream);

    enc_k<<<N_ / 16, 256, 0, stream>>>(x_in, enc_w, enc_b, x0);
    kq_k <<<N_ / 16, 256, 0, stream>>>(x0, wk_w, wk_b, wq_w, wq_b, kx, qx);
    count_k<<<(E + 255) / 256, 256, 0, stream>>>(edges, deg, E);
    scan_k<<<1, 256, 0, stream>>>(deg, row_ptr, row_fill);
    score_place_k<<<(E * 16 + 255) / 256, 256, 0, stream>>>(edges, kx, qx, row_fill, csr_v, csr_w, E);
    dedup_k<<<N_ / 4, 256, 0, stream>>>(row_ptr, csr_v, csr_w, vw);

    float* xa = x0;
    for (int s = 0; s < STEPS_; ++s) {
        step_k<<<N_ / 4, 256, 0, stream>>>(xa, (xa == x0) ? xb : x0, row_ptr, vw);
        xa = (xa == x0) ? xb : x0;
    }
    dec_k<<<N_ / 16, 256, 0, stream>>>(xa, dec_w, dec_b, out);
}